// Round 19
// baseline (348.085 us; speedup 1.0000x reference)
//
#include <hip/hip_runtime.h>

#define K_NN 16
#define JITTER 1e-4f
#define NPTS 16384
#define M_IND 512
#define NTILES 528

__device__ __forceinline__ unsigned umin_(unsigned a, unsigned b) { return a < b ? a : b; }
__device__ __forceinline__ unsigned umax_(unsigned a, unsigned b) { return a > b ? a : b; }

// ds_swizzle offset must be a literal -> macro-expand all uses.
#define BC16I(x, K)  __builtin_amdgcn_ds_swizzle((x), (((K) << 5) | 0x10))   // bcast lane K of each 16-subgroup
#define BC16F(x, K)  __int_as_float(BC16I(__float_as_int(x), K))
#define XOR16I(x, X) __builtin_amdgcn_ds_swizzle((x), (((X) << 10) | 0x1F))  // xor butterfly
#define XOR16F(x, X) __int_as_float(XOR16I(__float_as_int(x), X))

// DPP quad_perm exact xor^1 / xor^2 (VALU pipe, not DS)
#define DPP1I(x) __builtin_amdgcn_update_dpp((int)(x), (int)(x), 0xB1, 0xF, 0xF, true)
#define DPP2I(x) __builtin_amdgcn_update_dpp((int)(x), (int)(x), 0x4E, 0xF, 0xF, true)
#define DPP1F(x) __int_as_float(DPP1I(__float_as_int(x)))
#define DPP2F(x) __int_as_float(DPP2I(__float_as_int(x)))

#define RADD16(v) { float _t; \
  _t = DPP1F(v);      (v) += _t; \
  _t = DPP2F(v);      (v) += _t; \
  _t = XOR16F((v), 4); (v) += _t; \
  _t = XOR16F((v), 8); (v) += _t; }

#define CEx(A_, a, b) { unsigned _l = umin_(A_[a], A_[b]); unsigned _h = umax_(A_[a], A_[b]); A_[a] = _l; A_[b] = _h; }

#define SORT8(A_, o) \
  CEx(A_, o+0,o+1) CEx(A_, o+2,o+3) CEx(A_, o+4,o+5) CEx(A_, o+6,o+7) \
  CEx(A_, o+0,o+2) CEx(A_, o+1,o+3) CEx(A_, o+4,o+6) CEx(A_, o+5,o+7) \
  CEx(A_, o+1,o+2) CEx(A_, o+5,o+6) \
  CEx(A_, o+0,o+4) CEx(A_, o+1,o+5) CEx(A_, o+2,o+6) CEx(A_, o+3,o+7) \
  CEx(A_, o+2,o+4) CEx(A_, o+3,o+5) \
  CEx(A_, o+1,o+2) CEx(A_, o+3,o+4) CEx(A_, o+5,o+6)

#define SORT16(A_) \
  SORT8(A_, 0) SORT8(A_, 8) \
  CEx(A_,0,15) CEx(A_,1,14) CEx(A_,2,13) CEx(A_,3,12) CEx(A_,4,11) CEx(A_,5,10) CEx(A_,6,9) CEx(A_,7,8) \
  CEx(A_,0,4) CEx(A_,1,5) CEx(A_,2,6) CEx(A_,3,7) CEx(A_,8,12) CEx(A_,9,13) CEx(A_,10,14) CEx(A_,11,15) \
  CEx(A_,0,2) CEx(A_,1,3) CEx(A_,4,6) CEx(A_,5,7) CEx(A_,8,10) CEx(A_,9,11) CEx(A_,12,14) CEx(A_,13,15) \
  CEx(A_,0,1) CEx(A_,2,3) CEx(A_,4,5) CEx(A_,6,7) CEx(A_,8,9) CEx(A_,10,11) CEx(A_,12,13) CEx(A_,14,15)

#define BSORT16(A_) \
  CEx(A_,0,8) CEx(A_,1,9) CEx(A_,2,10) CEx(A_,3,11) CEx(A_,4,12) CEx(A_,5,13) CEx(A_,6,14) CEx(A_,7,15) \
  CEx(A_,0,4) CEx(A_,1,5) CEx(A_,2,6) CEx(A_,3,7) CEx(A_,8,12) CEx(A_,9,13) CEx(A_,10,14) CEx(A_,11,15) \
  CEx(A_,0,2) CEx(A_,1,3) CEx(A_,4,6) CEx(A_,5,7) CEx(A_,8,10) CEx(A_,9,11) CEx(A_,12,14) CEx(A_,13,15) \
  CEx(A_,0,1) CEx(A_,2,3) CEx(A_,4,5) CEx(A_,6,7) CEx(A_,8,9) CEx(A_,10,11) CEx(A_,12,13) CEx(A_,14,15)

// merge my sorted 16-list with partner's; EXCH = lane-exchange expression
#define MERGE16_E(EXCH) { \
    unsigned ex[16]; \
    _Pragma("unroll") \
    for (int i = 0; i < 16; ++i) ex[i] = (unsigned)(EXCH((int)mg[i])); \
    unsigned nw[16]; \
    _Pragma("unroll") \
    for (int i = 0; i < 16; ++i) nw[i] = umin_(mg[i], ex[15 - i]); \
    _Pragma("unroll") \
    for (int i = 0; i < 16; ++i) mg[i] = nw[i]; \
    BSORT16(mg) }

#define EX1(x)  DPP1I(x)
#define EX2(x)  DPP2I(x)
#define EX4(x)  XOR16I(x, 4)
#define EX8(x)  XOR16I(x, 8)

#define PICK(I) { mySelKey = (q == (I)) ? mg[I] : mySelKey; }

#define GATH(I) { \
    int si = (int)(mg[I] & 511u); \
    const float* zr = &Zs[si * 12]; \
    float d2 = 0.f; \
    _Pragma("unroll") \
    for (int d = 0; d < 8; ++d) { float df = zq[d] - zr[d]; d2 = fmaf(df, df, d2); } \
    float v = var * __expf(-d2 * inv2); \
    if (q == (I)) v += JITTER; \
    c[I] = v; \
    sv[I] = Sp[si * 512 + mySel]; }

#define CHOLK(K) { \
    float dsq = BC16F(c[K], K); \
    float invd = rsqrtf(dsq); \
    invdreg[K] = invd; \
    bool eq = (q == (K)); bool gt = (q > (K)); \
    float yk = BC16F(rbs, K) * invd; \
    yy = fmaf(yk, yk, yy); \
    float Ljk = c[K] * invd; \
    float nr = fmaf(-Ljk, yk, rbs); \
    rbs = eq ? yk : (gt ? nr : rbs); \
    _Pragma("unroll") \
    for (int i = (K) + 1; i < 16; ++i) { \
        float Lik = BC16F(c[i], K) * invd; \
        float upd = fmaf(-Lik, Ljk, c[i]); \
        c[i] = eq ? Lik : (gt ? upd : c[i]); \
    } }

#define BWDK(K) { \
    float wk = BC16F(r2, K) * invdreg[K]; \
    if (q < (K)) r2 = fmaf(-c[K], wk, r2); \
    if (q == (K)) myW = wk; \
    t = fmaf(wk, sv[K], t); }

// ---- Single dispatch: S-tiles (blocks<528) || select -> spin -> solve ----
// Co-residency: launch_bounds(256,4) caps VGPR<=128 -> 4 waves/SIMD -> 4
// blocks/CU; LDS 24576 -> 6/CU; grid 1024 = 256 CU x 4 -> ALL co-resident.
__launch_bounds__(256, 4)
__global__ void vnngp_mono_kernel(const float* __restrict__ X,
                                  const float* __restrict__ Zg,
                                  const float* __restrict__ Lu_raw,
                                  const float* __restrict__ mu,
                                  const float* __restrict__ lls,
                                  const float* __restrict__ lvar,
                                  float* __restrict__ S,
                                  int* __restrict__ done,
                                  float* __restrict__ out) {
    __shared__ float smem[512 * 12];  // prep: tI/tJ (8320 B); later: Zs
    const int tid = threadIdx.x;

    if (blockIdx.x < NTILES) {
        // ---- S tile (ti,tj), tj<=ti; mirror off-diag (symmetry) ----
        float (*tI)[65] = (float (*)[65])smem;
        float (*tJ)[65] = (float (*)[65])(smem + 16 * 65);
        int b = blockIdx.x;
        int ti = (int)((sqrtf(8.f * (float)b + 1.f) - 1.f) * 0.5f);
        while ((ti + 1) * (ti + 2) / 2 <= b) ++ti;
        while (ti * (ti + 1) / 2 > b) --ti;
        int tj = b - ti * (ti + 1) / 2;
        const int tx = tid & 15, ty = tid >> 4;
        const int bi = ti * 16, bj = tj * 16;
        float acc = 0.f;
        for (int k0 = 0; k0 < 512; k0 += 64) {
#pragma unroll
            for (int p = 0; p < 4; ++p) {
                int e = tid + p * 256;   // 16 rows x 64 cols
                int r = e >> 6, cc = e & 63;
                int col = k0 + cc;
                int rowi = bi + r;
                float v = Lu_raw[rowi * 512 + col];
                v = (col < rowi) ? v : ((col == rowi) ? __expf(v) : 0.f);
                tI[r][cc] = v;
                int rowj = bj + r;
                float w = Lu_raw[rowj * 512 + col];
                w = (col < rowj) ? w : ((col == rowj) ? __expf(w) : 0.f);
                tJ[r][cc] = w;
            }
            __syncthreads();
#pragma unroll
            for (int kk = 0; kk < 64; ++kk)
                acc = fmaf(tI[ty][kk], tJ[tx][kk], acc);
            __syncthreads();
        }
        S[(bi + ty) * 512 + (bj + tx)] = acc;
        if (ti != tj) S[(bj + tx) * 512 + (bi + ty)] = acc;
        __syncthreads();                       // all tile stores issued
        if (tid == 0) { __threadfence(); atomicAdd(done, 1); }
    }
    __syncthreads();  // smem reuse boundary (uniform per block)

    // ---- stage Zs ----
    float* Zs = smem;  // 8 dims, stride 12 (48B, 2-way-free banks)
    for (int e = tid; e < 512; e += 256) {
        float4 a = ((const float4*)Zg)[e * 2];
        float4 b = ((const float4*)Zg)[e * 2 + 1];
        *(float4*)&Zs[e * 12] = a;
        *(float4*)&Zs[e * 12 + 4] = b;
    }
    __syncthreads();

    const int q = tid & 15;
    const int n = blockIdx.x * 16 + (tid >> 4);

    const float ls = __expf(lls[0]);
    const float var = __expf(lvar[0]);
    const float inv2 = 0.5f / (ls * ls);

    const float4 x0 = ((const float4*)X)[n * 2];
    const float4 x1 = ((const float4*)X)[n * 2 + 1];
    const float xv[8] = {x0.x, x0.y, x0.z, x0.w, x1.x, x1.y, x1.z, x1.w};

    // ---- select: 32 candidates/lane, diff-form d2 ----
    unsigned sA[16], sB[16];
#pragma unroll
    for (int slot = 0; slot < 32; ++slot) {
        const float* zr = &Zs[(slot * 16 + q) * 12];
        float d2 = 0.f;
#pragma unroll
        for (int d = 0; d < 8; ++d) {
            float df = xv[d] - zr[d];
            d2 = fmaf(df, df, d2);
        }
        unsigned ki = umin_((unsigned)(d2 * 32768.0f), 0x7FFFFFu);
        unsigned key = (ki << 9) | (unsigned)(slot * 16 + q);
        if (slot < 16) sA[slot] = key; else sB[slot - 16] = key;
    }
    SORT16(sA)
    SORT16(sB)

    unsigned mg[16];
#pragma unroll
    for (int i = 0; i < 16; ++i) mg[i] = umin_(sA[i], sB[15 - i]);
    BSORT16(mg)

    MERGE16_E(EX1)
    MERGE16_E(EX2)
    MERGE16_E(EX4)
    MERGE16_E(EX8)

    unsigned mySelKey = mg[0];
    PICK(1) PICK(2) PICK(3) PICK(4) PICK(5) PICK(6) PICK(7)
    PICK(8) PICK(9) PICK(10) PICK(11) PICK(12) PICK(13) PICK(14) PICK(15)

    // ---- wait for all S tiles (normally already satisfied: prep ~2.5us
    //      finished under select ~24us). Guarded: no infinite hang. ----
    if (tid == 0) {
        int guard = 0;
        while (__hip_atomic_load(done, __ATOMIC_ACQUIRE, __HIP_MEMORY_SCOPE_AGENT) < NTILES
               && ++guard < (1 << 24)) {}
    }
    __syncthreads();
    __threadfence();  // invalidate caches before reading S

    // ---- solve (in-wave; mg[] replicated across the group) ----
    const float* Sp = S;
    const int mySel = (int)(mySelKey & 511u);
    const float d2q = (float)(mySelKey >> 9) * (1.0f / 32768.0f);
    const float myKxz = var * __expf(-d2q * inv2);
    const float myMu = mu[mySel];

    const float* zqp = &Zs[mySel * 12];
    float zq[8];
#pragma unroll
    for (int d = 0; d < 8; ++d) zq[d] = zqp[d];

    float c[16], sv[16];
    GATH(0) GATH(1) GATH(2) GATH(3) GATH(4) GATH(5) GATH(6) GATH(7)
    GATH(8) GATH(9) GATH(10) GATH(11) GATH(12) GATH(13) GATH(14) GATH(15)

    float invdreg[16];
    float rbs = myKxz;
    float yy = 0.f;
    CHOLK(0) CHOLK(1) CHOLK(2) CHOLK(3) CHOLK(4) CHOLK(5) CHOLK(6) CHOLK(7)
    CHOLK(8) CHOLK(9) CHOLK(10) CHOLK(11) CHOLK(12) CHOLK(13) CHOLK(14) CHOLK(15)

    float r2 = rbs;
    float myW = 0.f, t = 0.f;
    BWDK(15) BWDK(14) BWDK(13) BWDK(12) BWDK(11) BWDK(10) BWDK(9) BWDK(8)
    BWDK(7) BWDK(6) BWDK(5) BWDK(4) BWDK(3) BWDK(2) BWDK(1) BWDK(0)

    float p  = myW * t;
    float pm = myW * myMu;
    float pw = myW * myW;
    RADD16(p)
    RADD16(pm)
    RADD16(pw)

    if (q == 0) {
        float cov = var - (yy - JITTER * pw) + p;
        out[n] = pm;
        out[NPTS + n] = sqrtf(fmaxf(cov, 0.05f));
    }
}

extern "C" void kernel_launch(void* const* d_in, const int* in_sizes, int n_in,
                              void* d_out, int out_size, void* d_ws, size_t ws_size,
                              hipStream_t stream) {
    const float* X = (const float*)d_in[0];
    const float* Z = (const float*)d_in[1];
    const float* Lu_raw = (const float*)d_in[2];
    const float* mu = (const float*)d_in[3];
    const float* lls = (const float*)d_in[4];
    const float* lvar = (const float*)d_in[5];
    float* out = (float*)d_out;

    float* S = (float*)d_ws;                 // 1 MB
    int* done = (int*)(S + M_IND * M_IND);   // 4 B counter (reset every call)

    hipMemsetAsync(done, 0, sizeof(int), stream);
    vnngp_mono_kernel<<<NPTS / 16, 256, 0, stream>>>(X, Z, Lu_raw, mu, lls, lvar,
                                                     S, done, out);
}

// Round 20
// 41.783 us; speedup vs baseline: 8.3309x; 8.3309x over previous
//
#include <hip/hip_runtime.h>

#define K_NN 16
#define JITTER 1e-4f
#define NPTS 16384
#define M_IND 512

__device__ __forceinline__ unsigned umin_(unsigned a, unsigned b) { return a < b ? a : b; }
__device__ __forceinline__ unsigned umax_(unsigned a, unsigned b) { return a > b ? a : b; }

// ds_swizzle offset must be a literal -> macro-expand all uses.
#define BC16I(x, K)  __builtin_amdgcn_ds_swizzle((x), (((K) << 5) | 0x10))   // bcast lane K of each 16-subgroup
#define BC16F(x, K)  __int_as_float(BC16I(__float_as_int(x), K))
#define XOR16I(x, X) __builtin_amdgcn_ds_swizzle((x), (((X) << 10) | 0x1F))  // xor butterfly
#define XOR16F(x, X) __int_as_float(XOR16I(__float_as_int(x), X))

// DPP quad_perm exact xor^1 / xor^2 (VALU pipe, not DS)
#define DPP1I(x) __builtin_amdgcn_update_dpp((int)(x), (int)(x), 0xB1, 0xF, 0xF, true)
#define DPP2I(x) __builtin_amdgcn_update_dpp((int)(x), (int)(x), 0x4E, 0xF, 0xF, true)
#define DPP1F(x) __int_as_float(DPP1I(__float_as_int(x)))
#define DPP2F(x) __int_as_float(DPP2I(__float_as_int(x)))

#define RADD16(v) { float _t; \
  _t = DPP1F(v);      (v) += _t; \
  _t = DPP2F(v);      (v) += _t; \
  _t = XOR16F((v), 4); (v) += _t; \
  _t = XOR16F((v), 8); (v) += _t; }

#define CEx(A_, a, b) { unsigned _l = umin_(A_[a], A_[b]); unsigned _h = umax_(A_[a], A_[b]); A_[a] = _l; A_[b] = _h; }

#define SORT8(A_, o) \
  CEx(A_, o+0,o+1) CEx(A_, o+2,o+3) CEx(A_, o+4,o+5) CEx(A_, o+6,o+7) \
  CEx(A_, o+0,o+2) CEx(A_, o+1,o+3) CEx(A_, o+4,o+6) CEx(A_, o+5,o+7) \
  CEx(A_, o+1,o+2) CEx(A_, o+5,o+6) \
  CEx(A_, o+0,o+4) CEx(A_, o+1,o+5) CEx(A_, o+2,o+6) CEx(A_, o+3,o+7) \
  CEx(A_, o+2,o+4) CEx(A_, o+3,o+5) \
  CEx(A_, o+1,o+2) CEx(A_, o+3,o+4) CEx(A_, o+5,o+6)

#define SORT16(A_) \
  SORT8(A_, 0) SORT8(A_, 8) \
  CEx(A_,0,15) CEx(A_,1,14) CEx(A_,2,13) CEx(A_,3,12) CEx(A_,4,11) CEx(A_,5,10) CEx(A_,6,9) CEx(A_,7,8) \
  CEx(A_,0,4) CEx(A_,1,5) CEx(A_,2,6) CEx(A_,3,7) CEx(A_,8,12) CEx(A_,9,13) CEx(A_,10,14) CEx(A_,11,15) \
  CEx(A_,0,2) CEx(A_,1,3) CEx(A_,4,6) CEx(A_,5,7) CEx(A_,8,10) CEx(A_,9,11) CEx(A_,12,14) CEx(A_,13,15) \
  CEx(A_,0,1) CEx(A_,2,3) CEx(A_,4,5) CEx(A_,6,7) CEx(A_,8,9) CEx(A_,10,11) CEx(A_,12,13) CEx(A_,14,15)

#define BSORT16(A_) \
  CEx(A_,0,8) CEx(A_,1,9) CEx(A_,2,10) CEx(A_,3,11) CEx(A_,4,12) CEx(A_,5,13) CEx(A_,6,14) CEx(A_,7,15) \
  CEx(A_,0,4) CEx(A_,1,5) CEx(A_,2,6) CEx(A_,3,7) CEx(A_,8,12) CEx(A_,9,13) CEx(A_,10,14) CEx(A_,11,15) \
  CEx(A_,0,2) CEx(A_,1,3) CEx(A_,4,6) CEx(A_,5,7) CEx(A_,8,10) CEx(A_,9,11) CEx(A_,12,14) CEx(A_,13,15) \
  CEx(A_,0,1) CEx(A_,2,3) CEx(A_,4,5) CEx(A_,6,7) CEx(A_,8,9) CEx(A_,10,11) CEx(A_,12,13) CEx(A_,14,15)

// merge my sorted 16-list with partner's; EXCH = lane-exchange expression
#define MERGE16_E(EXCH) { \
    unsigned ex[16]; \
    _Pragma("unroll") \
    for (int i = 0; i < 16; ++i) ex[i] = (unsigned)(EXCH((int)mg[i])); \
    unsigned nw[16]; \
    _Pragma("unroll") \
    for (int i = 0; i < 16; ++i) nw[i] = umin_(mg[i], ex[15 - i]); \
    _Pragma("unroll") \
    for (int i = 0; i < 16; ++i) mg[i] = nw[i]; \
    BSORT16(mg) }

#define EX1(x)  DPP1I(x)
#define EX2(x)  DPP2I(x)
#define EX4(x)  XOR16I(x, 4)
#define EX8(x)  XOR16I(x, 8)

#define PICK(I) { mySelKey = (q == (I)) ? mg[I] : mySelKey; }

// ---- Prep: S = Lu * Lu^T, lower-triangle tiles only (528 blocks) --------
// S is symmetric: compute tile (ti,tj), tj<=ti, mirror the off-diag tile.
__global__ void vnngp_prep_kernel(const float* __restrict__ Lu_raw,
                                  float* __restrict__ S) {
    __shared__ float tI[16][65];
    __shared__ float tJ[16][65];
    // decode triangular index: blockIdx.x -> (ti,tj), tj <= ti, ti in [0,32)
    int b = blockIdx.x;
    int ti = (int)((sqrtf(8.f * (float)b + 1.f) - 1.f) * 0.5f);
    while ((ti + 1) * (ti + 2) / 2 <= b) ++ti;
    while (ti * (ti + 1) / 2 > b) --ti;
    int tj = b - ti * (ti + 1) / 2;

    const int tx = threadIdx.x & 15, ty = threadIdx.x >> 4;
    const int bi = ti * 16;
    const int bj = tj * 16;
    float acc = 0.f;
    for (int k0 = 0; k0 < 512; k0 += 64) {
#pragma unroll
        for (int p = 0; p < 4; ++p) {
            int e = threadIdx.x + p * 256;   // 0..1023 = 16 rows x 64 cols
            int r = e >> 6, cc = e & 63;
            int col = k0 + cc;
            int rowi = bi + r;
            float v = Lu_raw[rowi * 512 + col];
            v = (col < rowi) ? v : ((col == rowi) ? __expf(v) : 0.f);
            tI[r][cc] = v;
            int rowj = bj + r;
            float w = Lu_raw[rowj * 512 + col];
            w = (col < rowj) ? w : ((col == rowj) ? __expf(w) : 0.f);
            tJ[r][cc] = w;
        }
        __syncthreads();
#pragma unroll
        for (int kk = 0; kk < 64; ++kk)
            acc = fmaf(tI[ty][kk], tJ[tx][kk], acc);
        __syncthreads();
    }
    S[(bi + ty) * 512 + (bj + tx)] = acc;
    if (ti != tj) S[(bj + tx) * 512 + (bi + ty)] = acc;  // mirror (symmetry)
}

// ---------------- Fused select+solve: 4 points/wave, 16-lane groups ------
#define GATH(I) { \
    int si = (int)(mg[I] & 511u); \
    const float* zr = &Zs[si * 12]; \
    float d2 = 0.f; \
    _Pragma("unroll") \
    for (int d = 0; d < 8; ++d) { float df = zq[d] - zr[d]; d2 = fmaf(df, df, d2); } \
    float v = var * __expf(-d2 * inv2); \
    if (q == (I)) v += JITTER; \
    c[I] = v; \
    sv[I] = Sp[si * 512 + mySel]; }

#define CHOLK(K) { \
    float dsq = BC16F(c[K], K); \
    float invd = rsqrtf(dsq); \
    invdreg[K] = invd; \
    bool eq = (q == (K)); bool gt = (q > (K)); \
    float yk = BC16F(rbs, K) * invd; \
    yy = fmaf(yk, yk, yy); \
    float Ljk = c[K] * invd; \
    float nr = fmaf(-Ljk, yk, rbs); \
    rbs = eq ? yk : (gt ? nr : rbs); \
    _Pragma("unroll") \
    for (int i = (K) + 1; i < 16; ++i) { \
        float Lik = BC16F(c[i], K) * invd; \
        float upd = fmaf(-Lik, Ljk, c[i]); \
        c[i] = eq ? Lik : (gt ? upd : c[i]); \
    } }

#define BWDK(K) { \
    float wk = BC16F(r2, K) * invdreg[K]; \
    if (q < (K)) r2 = fmaf(-c[K], wk, r2); \
    if (q == (K)) myW = wk; \
    t = fmaf(wk, sv[K], t); }

__launch_bounds__(256, 4)
__global__ void vnngp_fused_kernel(const float* __restrict__ X,
                                   const float* __restrict__ Zg,
                                   const float* __restrict__ mu,
                                   const float* __restrict__ lls,
                                   const float* __restrict__ lvar,
                                   const float* __restrict__ Sp,
                                   float* __restrict__ out) {
    __shared__ float Zs[512 * 12];  // 8 dims, stride 12 (48B, 2-way-free banks)
    const int tid = threadIdx.x;
    for (int e = tid; e < 512; e += 256) {
        float4 a = ((const float4*)Zg)[e * 2];
        float4 b = ((const float4*)Zg)[e * 2 + 1];
        *(float4*)&Zs[e * 12] = a;
        *(float4*)&Zs[e * 12 + 4] = b;
    }
    __syncthreads();

    const int q = tid & 15;
    const int n = blockIdx.x * 16 + (tid >> 4);

    const float ls = __expf(lls[0]);
    const float var = __expf(lvar[0]);
    const float inv2 = 0.5f / (ls * ls);

    const float4 x0 = ((const float4*)X)[n * 2];
    const float4 x1 = ((const float4*)X)[n * 2 + 1];
    const float xv[8] = {x0.x, x0.y, x0.z, x0.w, x1.x, x1.y, x1.z, x1.w};

    // ---- select: 32 candidates/lane, diff-form d2 (2x ds_read_b128/slot) ----
    unsigned sA[16], sB[16];
#pragma unroll
    for (int slot = 0; slot < 32; ++slot) {
        const float* zr = &Zs[(slot * 16 + q) * 12];
        float d2 = 0.f;
#pragma unroll
        for (int d = 0; d < 8; ++d) {
            float df = xv[d] - zr[d];
            d2 = fmaf(df, df, d2);
        }
        unsigned ki = umin_((unsigned)(d2 * 32768.0f), 0x7FFFFFu);
        unsigned key = (ki << 9) | (unsigned)(slot * 16 + q);
        if (slot < 16) sA[slot] = key; else sB[slot - 16] = key;
    }
    SORT16(sA)
    SORT16(sB)

    unsigned mg[16];
#pragma unroll
    for (int i = 0; i < 16; ++i) mg[i] = umin_(sA[i], sB[15 - i]);
    BSORT16(mg)

    MERGE16_E(EX1)
    MERGE16_E(EX2)
    MERGE16_E(EX4)
    MERGE16_E(EX8)

    unsigned mySelKey = mg[0];
    PICK(1) PICK(2) PICK(3) PICK(4) PICK(5) PICK(6) PICK(7)
    PICK(8) PICK(9) PICK(10) PICK(11) PICK(12) PICK(13) PICK(14) PICK(15)

    // ---- solve (in-wave; mg[] replicated across the group) ----
    const int mySel = (int)(mySelKey & 511u);
    const float d2q = (float)(mySelKey >> 9) * (1.0f / 32768.0f);
    const float myKxz = var * __expf(-d2q * inv2);
    const float myMu = mu[mySel];

    const float* zqp = &Zs[mySel * 12];
    float zq[8];
#pragma unroll
    for (int d = 0; d < 8; ++d) zq[d] = zqp[d];

    float c[16], sv[16];
    GATH(0) GATH(1) GATH(2) GATH(3) GATH(4) GATH(5) GATH(6) GATH(7)
    GATH(8) GATH(9) GATH(10) GATH(11) GATH(12) GATH(13) GATH(14) GATH(15)

    float invdreg[16];
    float rbs = myKxz;
    float yy = 0.f;
    CHOLK(0) CHOLK(1) CHOLK(2) CHOLK(3) CHOLK(4) CHOLK(5) CHOLK(6) CHOLK(7)
    CHOLK(8) CHOLK(9) CHOLK(10) CHOLK(11) CHOLK(12) CHOLK(13) CHOLK(14) CHOLK(15)

    float r2 = rbs;
    float myW = 0.f, t = 0.f;
    BWDK(15) BWDK(14) BWDK(13) BWDK(12) BWDK(11) BWDK(10) BWDK(9) BWDK(8)
    BWDK(7) BWDK(6) BWDK(5) BWDK(4) BWDK(3) BWDK(2) BWDK(1) BWDK(0)

    float p  = myW * t;
    float pm = myW * myMu;
    float pw = myW * myW;
    RADD16(p)
    RADD16(pm)
    RADD16(pw)

    if (q == 0) {
        float cov = var - (yy - JITTER * pw) + p;
        out[n] = pm;
        out[NPTS + n] = sqrtf(fmaxf(cov, 0.05f));
    }
}

extern "C" void kernel_launch(void* const* d_in, const int* in_sizes, int n_in,
                              void* d_out, int out_size, void* d_ws, size_t ws_size,
                              hipStream_t stream) {
    const float* X = (const float*)d_in[0];
    const float* Z = (const float*)d_in[1];
    const float* Lu_raw = (const float*)d_in[2];
    const float* mu = (const float*)d_in[3];
    const float* lls = (const float*)d_in[4];
    const float* lvar = (const float*)d_in[5];
    float* out = (float*)d_out;

    float* S = (float*)d_ws;  // 512*512 floats = 1 MB

    vnngp_prep_kernel<<<528, 256, 0, stream>>>(Lu_raw, S);
    vnngp_fused_kernel<<<NPTS / 16, 256, 0, stream>>>(X, Z, mu, lls, lvar, S, out);
}